// Round 14
// baseline (308.683 us; speedup 1.0000x reference)
//
#include <hip/hip_runtime.h>
#include <hip/hip_bf16.h>
#include <math.h>

// CausalFullAttention: out[b,l,h,d] = softmax_s( 0.125*(q.k + bias[l,s]), s<=l ) @ V
// B=4 L=S=2048 H=8 E=D=64, fp32 in/out, bf16 MFMA compute.
// R13: ABLATION ROUND. Four variants of R10 launched sequentially (full runs LAST and
//      owns d_out): shell (staging+barriers+bias), nopv (+QK^T), nosm (+PV, no softmax),
//      full (=R10). Per-dispatch rocprof durations = chain breakdown.

typedef __bf16 bf16x8 __attribute__((ext_vector_type(8)));
typedef __bf16 bf16x4 __attribute__((ext_vector_type(4)));
typedef __bf16 bf16x2 __attribute__((ext_vector_type(2)));
typedef float  f32x4  __attribute__((ext_vector_type(4)));
typedef unsigned int u32;
typedef u32 u32x4 __attribute__((ext_vector_type(4)));

#define NB 4
#define NL 2048
#define NS 2048
#define NH 8
#define NE 64
#define ND 64

__device__ __forceinline__ int swz(int d) { return ((d ^ (d >> 3)) & 7) << 3; }

__device__ __forceinline__ u32 cvtpk(float lo, float hi) {
    u32 r;
    asm("v_cvt_pk_bf16_f32 %0, %1, %2" : "=v"(r) : "v"(lo), "v"(hi));
    return r;
}
__device__ __forceinline__ float bpermf(int srclane, float v) {
    return __uint_as_float((u32)__builtin_amdgcn_ds_bpermute(srclane << 2, (int)__float_as_uint(v)));
}
__device__ __forceinline__ u32 bpermu(int srclane, u32 v) {
    return (u32)__builtin_amdgcn_ds_bpermute(srclane << 2, (int)v);
}

__device__ __forceinline__ bf16x8 cvt8s(f32x4 a, f32x4 b, float sc) {
    bf16x8 r;
    r[0]=(__bf16)(a[0]*sc); r[1]=(__bf16)(a[1]*sc); r[2]=(__bf16)(a[2]*sc); r[3]=(__bf16)(a[3]*sc);
    r[4]=(__bf16)(b[0]*sc); r[5]=(__bf16)(b[1]*sc); r[6]=(__bf16)(b[2]*sc); r[7]=(__bf16)(b[3]*sc);
    return r;
}
__device__ __forceinline__ bf16x8 cvt8(f32x4 a, f32x4 b) {
    bf16x8 r;
    r[0]=(__bf16)a[0]; r[1]=(__bf16)a[1]; r[2]=(__bf16)a[2]; r[3]=(__bf16)a[3];
    r[4]=(__bf16)b[0]; r[5]=(__bf16)b[1]; r[6]=(__bf16)b[2]; r[7]=(__bf16)b[3];
    return r;
}

// CUT: 0=full(R10), 1=noSM (P=raw pack), 2=noPV (o+=s), 3=shell (o+=bias)
template<int CUT>
__device__ __forceinline__ void fa_body(const float* __restrict__ Q,
                                        const float* __restrict__ K,
                                        const float* __restrict__ V,
                                        const float* __restrict__ Bias,
                                        float* __restrict__ Out)
{
    __shared__ __bf16 Klds[2][64][72];
    __shared__ __bf16 Vlds[2][64][64];

    const int tid  = threadIdx.x;
    const int w    = tid >> 6, lane = tid & 63;
    const int g    = lane >> 4, li = lane & 15;

    const int id = blockIdx.x;
    int bh, qp_;
    if (id < 256) { bh = id >> 4;                qp_ = 15 - (id & 15); }
    else          { bh = 16 + ((id - 256) >> 4); qp_ = id & 15;        }
    const int b   = bh >> 3, h = bh & 7;
    const int qb  = qp_ << 7;
    const int qw  = qb + (w << 4);

    const float SC = 0.125f * 1.44269504088896340736f;

    bf16x8 qa[2];
    {
        const float* qp = Q + (((size_t)(b * NL + qw + li)) * NH + h) * NE;
        #pragma unroll
        for (int eh = 0; eh < 2; ++eh) {
            const int e0 = eh * 32 + g * 8;
            f32x4 f0 = *(const f32x4*)(qp + e0);
            f32x4 f1 = *(const f32x4*)(qp + e0 + 4);
            qa[eh] = cvt8s(f0, f1, SC);
        }
    }

    f32x4 o[4] = {};
    float m_run = -INFINITY, l_run = 0.0f;

    const int ntiles = (qb >> 6) + 2;

    const int skv = tid >> 3,        se0 = (tid & 7) << 3;
    const int vkv = (tid >> 4) << 1, vd0 = (tid & 15) << 2;

    const float* kp0 = K + (((size_t)(b * NS + skv)) * NH + h) * NE + se0;
    const float* vp0 = V + (((size_t)(b * NS + vkv)) * NH + h) * ND + vd0;
    const float* bp0 = Bias + (size_t)(qw + li) * NS + g * 4;

    f32x4 ka0, ka1, va0, va1;
    f32x4 bc[4], bn[4];

    auto write_lds = [&](int buf) {
        *(bf16x8*)&Klds[buf][skv][se0] = cvt8(ka0, ka1);
        #pragma unroll
        for (int dd = 0; dd < 4; ++dd) {
            bf16x2 cc; cc[0] = (__bf16)va0[dd]; cc[1] = (__bf16)va1[dd];
            *(bf16x2*)&Vlds[buf][vd0 + dd][vkv ^ swz(vd0 + dd)] = cc;
        }
    };

    ka0 = ((const f32x4*)kp0)[0]; ka1 = ((const f32x4*)kp0)[1];
    va0 = *(const f32x4*)(vp0);   va1 = *(const f32x4*)(vp0 + NH * ND);
    #pragma unroll
    for (int c = 0; c < 4; ++c) bc[c] = *(const f32x4*)(bp0 + c * 16);
    write_lds(0);
    __syncthreads();

    for (int t = 0; t < ntiles; ++t) {
        const int cur = t & 1;
        const bool more = (t + 1 < ntiles);

        if (more) {
            const int kvn = (t + 1) << 6;
            const float* kp = kp0 + (size_t)kvn * (NH * NE);
            ka0 = ((const f32x4*)kp)[0]; ka1 = ((const f32x4*)kp)[1];
            const float* vp = vp0 + (size_t)kvn * (NH * ND);
            va0 = *(const f32x4*)(vp);   va1 = *(const f32x4*)(vp + NH * ND);
            #pragma unroll
            for (int c = 0; c < 4; ++c) bn[c] = *(const f32x4*)(bp0 + kvn + c * 16);
        }

        const int kv0 = t << 6;
        if (kv0 <= qw + 15) {
            if constexpr (CUT == 3) {
                // shell: keep bias regs live through o (stored at end)
                #pragma unroll
                for (int c = 0; c < 4; ++c) o[c] += bc[c];
            } else {
                f32x4 s[4];
                #pragma unroll
                for (int c = 0; c < 4; ++c) {
                    f32x4 acc = {};
                    #pragma unroll
                    for (int eh = 0; eh < 2; ++eh) {
                        bf16x8 kb = *(const bf16x8*)&Klds[cur][c * 16 + li][eh * 32 + g * 8];
                        acc = __builtin_amdgcn_mfma_f32_16x16x32_bf16(kb, qa[eh], acc, 0, 0, 0);
                    }
                    s[c] = acc;
                }
                const int lg = qw + li;
                if (kv0 + 63 > qw) {
                    #pragma unroll
                    for (int c = 0; c < 4; ++c)
                        #pragma unroll
                        for (int r = 0; r < 4; ++r) {
                            const int sg = kv0 + c * 16 + g * 4 + r;
                            s[c][r] = (sg <= lg) ? fmaf(bc[c][r], SC, s[c][r]) : -INFINITY;
                        }
                } else {
                    #pragma unroll
                    for (int c = 0; c < 4; ++c)
                        #pragma unroll
                        for (int r = 0; r < 4; ++r)
                            s[c][r] = fmaf(bc[c][r], SC, s[c][r]);
                }

                if constexpr (CUT == 2) {
                    // noPV: QK^T result kept live via o accumulation
                    #pragma unroll
                    for (int c = 0; c < 4; ++c) o[c] += s[c];
                } else {
                    if constexpr (CUT == 0) {
                        // full softmax (R10)
                        float pm = fmaxf(
                            fmaxf(fmaxf(fmaxf(s[0][0],s[0][1]),fmaxf(s[0][2],s[0][3])),
                                  fmaxf(fmaxf(s[1][0],s[1][1]),fmaxf(s[1][2],s[1][3]))),
                            fmaxf(fmaxf(fmaxf(s[2][0],s[2][1]),fmaxf(s[2][2],s[2][3])),
                                  fmaxf(fmaxf(s[3][0],s[3][1]),fmaxf(s[3][2],s[3][3]))));
                        pm = fmaxf(pm, __shfl_xor(pm, 16, 64));
                        pm = fmaxf(pm, __shfl_xor(pm, 32, 64));
                        if (!__all(pm <= m_run + 8.0f)) {
                            const float mn = fmaxf(m_run, pm);
                            const float corr = exp2f(m_run - mn);
                            m_run = mn; l_run *= corr;
                            #pragma unroll
                            for (int j = 0; j < 4; ++j) {
                                const float cj = bpermf(g * 20 + j, corr);
                                o[0][j] *= cj; o[1][j] *= cj; o[2][j] *= cj; o[3][j] *= cj;
                            }
                        }
                        #pragma unroll
                        for (int c = 0; c < 4; ++c)
                            #pragma unroll
                            for (int r = 0; r < 4; ++r)
                                s[c][r] = exp2f(s[c][r] - m_run);
                        float rs = ((s[0][0]+s[0][1])+(s[0][2]+s[0][3]))
                                 + ((s[1][0]+s[1][1])+(s[1][2]+s[1][3]))
                                 + ((s[2][0]+s[2][1])+(s[2][2]+s[2][3]))
                                 + ((s[3][0]+s[3][1])+(s[3][2]+s[3][3]));
                        rs += __shfl_xor(rs, 16, 64);
                        rs += __shfl_xor(rs, 32, 64);
                        l_run += rs;
                    }
                    // P -> bf16 A-frags
                    u32x4 pw0, pw1;
                    if constexpr (CUT == 0) {
                        const u32 w00 = cvtpk(s[0][0], s[0][1]), w01 = cvtpk(s[0][2], s[0][3]);
                        const u32 w10 = cvtpk(s[1][0], s[1][1]), w11 = cvtpk(s[1][2], s[1][3]);
                        const u32 w20 = cvtpk(s[2][0], s[2][1]), w21 = cvtpk(s[2][2], s[2][3]);
                        const u32 w30 = cvtpk(s[3][0], s[3][1]), w31 = cvtpk(s[3][2], s[3][3]);
                        const int slA = (((2 * g) & 3) << 4) | li;
                        const int slB = (((2 * g + 1) & 3) << 4) | li;
                        const bool hi = (g >= 2);
                        const u32 tA0a = bpermu(slA, w00), tA0b = bpermu(slA, w10);
                        const u32 tA1a = bpermu(slA, w01), tA1b = bpermu(slA, w11);
                        const u32 tB0a = bpermu(slB, w00), tB0b = bpermu(slB, w10);
                        const u32 tB1a = bpermu(slB, w01), tB1b = bpermu(slB, w11);
                        pw0[0] = hi ? tA0b : tA0a;
                        pw0[1] = hi ? tA1b : tA1a;
                        pw0[2] = hi ? tB0b : tB0a;
                        pw0[3] = hi ? tB1b : tB1a;
                        const u32 uA0a = bpermu(slA, w20), uA0b = bpermu(slA, w30);
                        const u32 uA1a = bpermu(slA, w21), uA1b = bpermu(slA, w31);
                        const u32 uB0a = bpermu(slB, w20), uB0b = bpermu(slB, w30);
                        const u32 uB1a = bpermu(slB, w21), uB1b = bpermu(slB, w31);
                        pw1[0] = hi ? uA0b : uA0a;
                        pw1[1] = hi ? uA1b : uA1a;
                        pw1[2] = hi ? uB0b : uB0a;
                        pw1[3] = hi ? uB1b : uB1a;
                    } else {
                        // noSM: pack raw scores directly (no cross-lane, wrong math, live chain)
                        pw0[0] = cvtpk(s[0][0], s[0][1]); pw0[1] = cvtpk(s[0][2], s[0][3]);
                        pw0[2] = cvtpk(s[1][0], s[1][1]); pw0[3] = cvtpk(s[1][2], s[1][3]);
                        pw1[0] = cvtpk(s[2][0], s[2][1]); pw1[1] = cvtpk(s[2][2], s[2][3]);
                        pw1[2] = cvtpk(s[3][0], s[3][1]); pw1[3] = cvtpk(s[3][2], s[3][3]);
                    }
                    const bf16x8 pa0 = __builtin_bit_cast(bf16x8, pw0);
                    const bf16x8 pa1 = __builtin_bit_cast(bf16x8, pw1);
                    #pragma unroll
                    for (int dt = 0; dt < 4; ++dt) {
                        const int d = dt * 16 + li;
                        bf16x8 v0 = *(const bf16x8*)&Vlds[cur][d][(g * 8) ^ swz(d)];
                        bf16x8 v1 = *(const bf16x8*)&Vlds[cur][d][(32 + g * 8) ^ swz(d)];
                        o[dt] = __builtin_amdgcn_mfma_f32_16x16x32_bf16(pa0, v0, o[dt], 0, 0, 0);
                        o[dt] = __builtin_amdgcn_mfma_f32_16x16x32_bf16(pa1, v1, o[dt], 0, 0, 0);
                    }
                }
            }
        }

        if (more) {
            __syncthreads();
            write_lds(cur ^ 1);
            __syncthreads();
            #pragma unroll
            for (int c = 0; c < 4; ++c) bc[c] = bn[c];
        }
    }

    #pragma unroll
    for (int j = 0; j < 4; ++j) {
        float inv = 1.0f;
        if constexpr (CUT == 0) {
            const float lj = bpermf(g * 20 + j, l_run);
            inv = 1.0f / lj;
        }
        const int lgq = qw + g * 4 + j;
        float* op = Out + (((size_t)(b * NL + lgq)) * NH + h) * ND + li;
        op[0]  = o[0][j] * inv;
        op[16] = o[1][j] * inv;
        op[32] = o[2][j] * inv;
        op[48] = o[3][j] * inv;
    }
}

__global__ __launch_bounds__(512) void fa_shell(const float* Q, const float* K,
    const float* V, const float* Bias, float* Out) { fa_body<3>(Q, K, V, Bias, Out); }
__global__ __launch_bounds__(512) void fa_nopv(const float* Q, const float* K,
    const float* V, const float* Bias, float* Out) { fa_body<2>(Q, K, V, Bias, Out); }
__global__ __launch_bounds__(512) void fa_nosm(const float* Q, const float* K,
    const float* V, const float* Bias, float* Out) { fa_body<1>(Q, K, V, Bias, Out); }
__global__ __launch_bounds__(512) void fa_full(const float* Q, const float* K,
    const float* V, const float* Bias, float* Out) { fa_body<0>(Q, K, V, Bias, Out); }

extern "C" void kernel_launch(void* const* d_in, const int* in_sizes, int n_in,
                              void* d_out, int out_size, void* d_ws, size_t ws_size,
                              hipStream_t stream)
{
    const float* Q    = (const float*)d_in[0];
    const float* K    = (const float*)d_in[1];
    const float* V    = (const float*)d_in[2];
    const float* Bias = (const float*)d_in[3];
    float* Out = (float*)d_out;
    dim3 grid(512);
    dim3 block(512);
    // Ablation: variants first (their d_out writes are overwritten), full LAST.
    fa_shell<<<grid, block, 0, stream>>>(Q, K, V, Bias, Out);
    fa_nopv <<<grid, block, 0, stream>>>(Q, K, V, Bias, Out);
    fa_nosm <<<grid, block, 0, stream>>>(Q, K, V, Bias, Out);
    fa_full <<<grid, block, 0, stream>>>(Q, K, V, Bias, Out);
}

// Round 15
// 93.914 us; speedup vs baseline: 3.2869x; 3.2869x over previous
//
#include <hip/hip_runtime.h>
#include <hip/hip_bf16.h>
#include <math.h>

// CausalFullAttention: out[b,l,h,d] = softmax_s( 0.125*(q.k + bias[l,s]), s<=l ) @ V
// B=4 L=S=2048 H=8 E=D=64, fp32 in/out, bf16 MFMA compute.
// R14: (1) K-row permutation in LDS so the swapped-QK^T C-layout IS the PV A-layout:
//      P re-frag = 8 cvt_pk, zero bpermutes. (2) single barrier per tile
//      (write(nxt) || compute(cur) -> one __syncthreads). Shell/grid/pairing = R10.

typedef __bf16 bf16x8 __attribute__((ext_vector_type(8)));
typedef __bf16 bf16x2 __attribute__((ext_vector_type(2)));
typedef float  f32x4  __attribute__((ext_vector_type(4)));
typedef unsigned int u32;
typedef u32 u32x4 __attribute__((ext_vector_type(4)));

#define NB 4
#define NL 2048
#define NS 2048
#define NH 8
#define NE 64
#define ND 64

__device__ __forceinline__ int swz(int d) { return ((d ^ (d >> 3)) & 7) << 3; }

__device__ __forceinline__ u32 cvtpk(float lo, float hi) {
    u32 r;
    asm("v_cvt_pk_bf16_f32 %0, %1, %2" : "=v"(r) : "v"(lo), "v"(hi));
    return r;   // [15:0]=bf16(lo), [31:16]=bf16(hi)
}
__device__ __forceinline__ float bpermf(int srclane, float v) {
    return __uint_as_float((u32)__builtin_amdgcn_ds_bpermute(srclane << 2, (int)__float_as_uint(v)));
}

__device__ __forceinline__ bf16x8 cvt8s(f32x4 a, f32x4 b, float sc) {
    bf16x8 r;
    r[0]=(__bf16)(a[0]*sc); r[1]=(__bf16)(a[1]*sc); r[2]=(__bf16)(a[2]*sc); r[3]=(__bf16)(a[3]*sc);
    r[4]=(__bf16)(b[0]*sc); r[5]=(__bf16)(b[1]*sc); r[6]=(__bf16)(b[2]*sc); r[7]=(__bf16)(b[3]*sc);
    return r;
}
__device__ __forceinline__ bf16x8 cvt8(f32x4 a, f32x4 b) {
    bf16x8 r;
    r[0]=(__bf16)a[0]; r[1]=(__bf16)a[1]; r[2]=(__bf16)a[2]; r[3]=(__bf16)a[3];
    r[4]=(__bf16)b[0]; r[5]=(__bf16)b[1]; r[6]=(__bf16)b[2]; r[7]=(__bf16)b[3];
    return r;
}

__global__ __launch_bounds__(512)
void fa_fwd(const float* __restrict__ Q, const float* __restrict__ K,
            const float* __restrict__ V, const float* __restrict__ Bias,
            float* __restrict__ Out)
{
    __shared__ __bf16 Klds[2][64][72];   // K tile, ROW-PERMUTED: K[kv] at row rho(kv)
    __shared__ __bf16 Vlds[2][64][64];   // V^T tile [d][kv], XOR slot swizzle

    const int tid  = threadIdx.x;
    const int w    = tid >> 6, lane = tid & 63;
    const int g    = lane >> 4, li = lane & 15;

    // 512 blocks, all resident (2/CU); complementary heavy/light pairing.
    const int id = blockIdx.x;
    int bh, qp_;
    if (id < 256) { bh = id >> 4;                qp_ = 15 - (id & 15); }
    else          { bh = 16 + ((id - 256) >> 4); qp_ = id & 15;        }
    const int b   = bh >> 3, h = bh & 7;
    const int qb  = qp_ << 7;
    const int qw  = qb + (w << 4);        // this wave's first q row

    const float SC = 0.125f * 1.44269504088896340736f;  // scale * log2(e)

    // Q fragments (B operand of swapped QK^T), pre-scaled
    bf16x8 qa[2];
    {
        const float* qp = Q + (((size_t)(b * NL + qw + li)) * NH + h) * NE;
        #pragma unroll
        for (int eh = 0; eh < 2; ++eh) {
            const int e0 = eh * 32 + g * 8;
            f32x4 f0 = *(const f32x4*)(qp + e0);
            f32x4 f1 = *(const f32x4*)(qp + e0 + 4);
            qa[eh] = cvt8s(f0, f1, SC);
        }
    }

    f32x4 o[4] = {};                      // O: row q = g*4+j, col d = dt*16+li
    float m_run = -INFINITY, l_run = 0.0f;   // per-lane, q-row = qw + li

    const int ntiles = (qb >> 6) + 2;     // kv tiles cover rows 0..qb+127 (>=2)

    // staging indices (512 threads)
    const int skv = tid >> 3,        se0 = (tid & 7) << 3;   // K: row, 8-float chunk
    const int vkv = (tid >> 4) << 1, vd0 = (tid & 15) << 2;  // V: 2kv x 4d sub-block
    // K row permutation: rho(kv) = (kv&32) | ((kv>>2)&1)<<4 | ((kv>>3)&3)<<2 | (kv&3)
    const int rho = (skv & 32) | (((skv >> 2) & 1) << 4) | (((skv >> 3) & 3) << 2) | (skv & 3);

    const float* kp0 = K + (((size_t)(b * NS + skv)) * NH + h) * NE + se0;
    const float* vp0 = V + (((size_t)(b * NS + vkv)) * NH + h) * ND + vd0;
    const float* bp0 = Bias + (size_t)(qw + li) * NS + g * 8;   // permuted-order base

    f32x4 ka0, ka1, va0, va1;             // stage regs (tile in flight)
    f32x4 bc[4], bn[4];                   // bias regs: [c] -> kv = 32(c>>1)+8g+4(c&1)+r

    auto issue_kv = [&](int T) {
        const float* kp = kp0 + (size_t)(T << 6) * (NH * NE);
        ka0 = ((const f32x4*)kp)[0]; ka1 = ((const f32x4*)kp)[1];
        const float* vp = vp0 + (size_t)(T << 6) * (NH * ND);
        va0 = *(const f32x4*)(vp); va1 = *(const f32x4*)(vp + NH * ND);
    };
    auto load_bias = [&](f32x4 (&bx)[4], int T) {
        const float* bp = bp0 + (T << 6);
        #pragma unroll
        for (int c = 0; c < 4; ++c)
            bx[c] = *(const f32x4*)(bp + ((c >> 1) << 5) + ((c & 1) << 2));
    };
    auto write_lds = [&](int buf) {
        *(bf16x8*)&Klds[buf][rho][se0] = cvt8(ka0, ka1);
        #pragma unroll
        for (int dd = 0; dd < 4; ++dd) {
            bf16x2 cc; cc[0] = (__bf16)va0[dd]; cc[1] = (__bf16)va1[dd];
            *(bf16x2*)&Vlds[buf][vd0 + dd][vkv ^ swz(vd0 + dd)] = cc;
        }
    };

    // ---- prologue: tile 0 staged, tile 1 in flight ----
    issue_kv(0);
    load_bias(bc, 0);
    write_lds(0);
    if (ntiles > 1) issue_kv(1);
    __syncthreads();

    for (int t = 0; t < ntiles; ++t) {
        const int cur = t & 1;
        const bool more = (t + 1 < ntiles);

        // write tile t+1 into the other buffer (regs from iter t-1/prologue),
        // then refill regs for tile t+2. No barrier before compute: different buffers.
        if (more) {
            load_bias(bn, t + 1);
            write_lds(cur ^ 1);
            if (t + 2 < ntiles) issue_kv(t + 2);
        }

        // compute tile t (wave-uniform causal skip)
        const int kv0 = t << 6;
        if (kv0 <= qw + 15) {
            // swapped QK^T on permuted K rows: s[c][r] = S[kv=kv0+32(c>>1)+8g+4(c&1)+r][q=qw+li]
            f32x4 s[4];
            #pragma unroll
            for (int c = 0; c < 4; ++c) {
                f32x4 acc = {};
                #pragma unroll
                for (int eh = 0; eh < 2; ++eh) {
                    bf16x8 kb = *(const bf16x8*)&Klds[cur][c * 16 + li][eh * 32 + g * 8];
                    acc = __builtin_amdgcn_mfma_f32_16x16x32_bf16(kb, qa[eh], acc, 0, 0, 0);
                }
                s[c] = acc;
            }
            const int lg = qw + li;
            if (kv0 + 63 > qw) {          // straddle: bias + causal select (permuted kv)
                #pragma unroll
                for (int c = 0; c < 4; ++c) {
                    const int kvb = kv0 + ((c >> 1) << 5) + (g << 3) + ((c & 1) << 2);
                    #pragma unroll
                    for (int r = 0; r < 4; ++r)
                        s[c][r] = (kvb + r <= lg) ? fmaf(bc[c][r], SC, s[c][r]) : -INFINITY;
                }
            } else {
                #pragma unroll
                for (int c = 0; c < 4; ++c)
                    #pragma unroll
                    for (int r = 0; r < 4; ++r)
                        s[c][r] = fmaf(bc[c][r], SC, s[c][r]);
            }
            // row stats: 15 in-lane + 2 shuffles (order-invariant under permutation)
            float pm = fmaxf(
                fmaxf(fmaxf(fmaxf(s[0][0],s[0][1]),fmaxf(s[0][2],s[0][3])),
                      fmaxf(fmaxf(s[1][0],s[1][1]),fmaxf(s[1][2],s[1][3]))),
                fmaxf(fmaxf(fmaxf(s[2][0],s[2][1]),fmaxf(s[2][2],s[2][3])),
                      fmaxf(fmaxf(s[3][0],s[3][1]),fmaxf(s[3][2],s[3][3]))));
            pm = fmaxf(pm, __shfl_xor(pm, 16, 64));
            pm = fmaxf(pm, __shfl_xor(pm, 32, 64));
            if (!__all(pm <= m_run + 8.0f)) {     // defer-max (T13)
                const float mn = fmaxf(m_run, pm);
                const float corr = exp2f(m_run - mn);
                m_run = mn; l_run *= corr;
                #pragma unroll
                for (int j = 0; j < 4; ++j) {
                    const float cj = bpermf(g * 20 + j, corr);
                    o[0][j] *= cj; o[1][j] *= cj; o[2][j] *= cj; o[3][j] *= cj;
                }
            }
            #pragma unroll
            for (int c = 0; c < 4; ++c)
                #pragma unroll
                for (int r = 0; r < 4; ++r)
                    s[c][r] = exp2f(s[c][r] - m_run);
            float rs = ((s[0][0]+s[0][1])+(s[0][2]+s[0][3]))
                     + ((s[1][0]+s[1][1])+(s[1][2]+s[1][3]))
                     + ((s[2][0]+s[2][1])+(s[2][2]+s[2][3]))
                     + ((s[3][0]+s[3][1])+(s[3][2]+s[3][3]));
            rs += __shfl_xor(rs, 16, 64);
            rs += __shfl_xor(rs, 32, 64);
            l_run += rs;
            // P -> PV A-frags: DIRECT pack (permutation already aligned kv order)
            u32x4 pw0, pw1;
            pw0[0] = cvtpk(s[0][0], s[0][1]); pw0[1] = cvtpk(s[0][2], s[0][3]);
            pw0[2] = cvtpk(s[1][0], s[1][1]); pw0[3] = cvtpk(s[1][2], s[1][3]);
            pw1[0] = cvtpk(s[2][0], s[2][1]); pw1[1] = cvtpk(s[2][2], s[2][3]);
            pw1[2] = cvtpk(s[3][0], s[3][1]); pw1[3] = cvtpk(s[3][2], s[3][3]);
            const bf16x8 pa0 = __builtin_bit_cast(bf16x8, pw0);
            const bf16x8 pa1 = __builtin_bit_cast(bf16x8, pw1);
            // PV: O += P @ V
            #pragma unroll
            for (int dt = 0; dt < 4; ++dt) {
                const int d = dt * 16 + li;
                bf16x8 v0 = *(const bf16x8*)&Vlds[cur][d][(g * 8) ^ swz(d)];
                bf16x8 v1 = *(const bf16x8*)&Vlds[cur][d][(32 + g * 8) ^ swz(d)];
                o[dt] = __builtin_amdgcn_mfma_f32_16x16x32_bf16(pa0, v0, o[dt], 0, 0, 0);
                o[dt] = __builtin_amdgcn_mfma_f32_16x16x32_bf16(pa1, v1, o[dt], 0, 0, 0);
            }
        }

        // single barrier per tile: separates this iter's reads/writes from next iter's
        if (more) {
            __syncthreads();
            #pragma unroll
            for (int c = 0; c < 4; ++c) bc[c] = bn[c];
        }
    }

    // ---- epilogue: transport l to O layout, normalize, store fp32 ----
    #pragma unroll
    for (int j = 0; j < 4; ++j) {
        const float lj = bpermf(g * 20 + j, l_run);   // src lane (g, li=g*4+j)
        const float inv = 1.0f / lj;
        const int lgq = qw + g * 4 + j;
        float* op = Out + (((size_t)(b * NL + lgq)) * NH + h) * ND + li;
        op[0]  = o[0][j] * inv;
        op[16] = o[1][j] * inv;
        op[32] = o[2][j] * inv;
        op[48] = o[3][j] * inv;
    }
}

extern "C" void kernel_launch(void* const* d_in, const int* in_sizes, int n_in,
                              void* d_out, int out_size, void* d_ws, size_t ws_size,
                              hipStream_t stream)
{
    const float* Q    = (const float*)d_in[0];
    const float* K    = (const float*)d_in[1];
    const float* V    = (const float*)d_in[2];
    const float* Bias = (const float*)d_in[3];
    // d_in[4] (attn_mask) is the static triu(k=1) causal mask - handled analytically.
    float* Out = (float*)d_out;
    dim3 grid(512);                  // remapped in-kernel (complementary pairing)
    dim3 block(512);
    fa_fwd<<<grid, block, 0, stream>>>(Q, K, V, Bias, Out);
}

// Round 16
// 90.613 us; speedup vs baseline: 3.4066x; 1.0364x over previous
//
#include <hip/hip_runtime.h>
#include <hip/hip_bf16.h>
#include <math.h>

// CausalFullAttention: out[b,l,h,d] = softmax_s( 0.125*(q.k + bias[l,s]), s<=l ) @ V
// B=4 L=S=2048 H=8 E=D=64, fp32 in/out, bf16 MFMA compute.
// R15: 2 tiles per barrier, 4 LDS buffers (68KB, still 2 blocks/CU). Period =
//      {compute t, t+1; stage t+2, t+3; ONE __syncthreads}. ntiles always even ->
//      no tail. K-perm direct-pack softmax (R14), pairing/grid unchanged.

typedef __bf16 bf16x8 __attribute__((ext_vector_type(8)));
typedef __bf16 bf16x2 __attribute__((ext_vector_type(2)));
typedef float  f32x4  __attribute__((ext_vector_type(4)));
typedef unsigned int u32;
typedef u32 u32x4 __attribute__((ext_vector_type(4)));

#define NB 4
#define NL 2048
#define NS 2048
#define NH 8
#define NE 64
#define ND 64

__device__ __forceinline__ int swz(int d) { return ((d ^ (d >> 3)) & 7) << 3; }

__device__ __forceinline__ u32 cvtpk(float lo, float hi) {
    u32 r;
    asm("v_cvt_pk_bf16_f32 %0, %1, %2" : "=v"(r) : "v"(lo), "v"(hi));
    return r;   // [15:0]=bf16(lo), [31:16]=bf16(hi)
}
__device__ __forceinline__ float bpermf(int srclane, float v) {
    return __uint_as_float((u32)__builtin_amdgcn_ds_bpermute(srclane << 2, (int)__float_as_uint(v)));
}

__device__ __forceinline__ bf16x8 cvt8s(f32x4 a, f32x4 b, float sc) {
    bf16x8 r;
    r[0]=(__bf16)(a[0]*sc); r[1]=(__bf16)(a[1]*sc); r[2]=(__bf16)(a[2]*sc); r[3]=(__bf16)(a[3]*sc);
    r[4]=(__bf16)(b[0]*sc); r[5]=(__bf16)(b[1]*sc); r[6]=(__bf16)(b[2]*sc); r[7]=(__bf16)(b[3]*sc);
    return r;
}
__device__ __forceinline__ bf16x8 cvt8(f32x4 a, f32x4 b) {
    bf16x8 r;
    r[0]=(__bf16)a[0]; r[1]=(__bf16)a[1]; r[2]=(__bf16)a[2]; r[3]=(__bf16)a[3];
    r[4]=(__bf16)b[0]; r[5]=(__bf16)b[1]; r[6]=(__bf16)b[2]; r[7]=(__bf16)b[3];
    return r;
}

__global__ __launch_bounds__(512)
void fa_fwd(const float* __restrict__ Q, const float* __restrict__ K,
            const float* __restrict__ V, const float* __restrict__ Bias,
            float* __restrict__ Out)
{
    __shared__ __bf16 Klds[4][64][72];   // K tile, ROW-PERMUTED; 4 buffers
    __shared__ __bf16 Vlds[4][64][64];   // V^T tile [d][kv], XOR slot swizzle; 4 buffers

    const int tid  = threadIdx.x;
    const int w    = tid >> 6, lane = tid & 63;
    const int g    = lane >> 4, li = lane & 15;

    // 512 blocks, all resident (2/CU); complementary heavy/light pairing.
    const int id = blockIdx.x;
    int bh, qp_;
    if (id < 256) { bh = id >> 4;                qp_ = 15 - (id & 15); }
    else          { bh = 16 + ((id - 256) >> 4); qp_ = id & 15;        }
    const int b   = bh >> 3, h = bh & 7;
    const int qb  = qp_ << 7;
    const int qw  = qb + (w << 4);        // this wave's first q row

    const float SC = 0.125f * 1.44269504088896340736f;  // scale * log2(e)

    // Q fragments (B operand of swapped QK^T), pre-scaled
    bf16x8 qa[2];
    {
        const float* qp = Q + (((size_t)(b * NL + qw + li)) * NH + h) * NE;
        #pragma unroll
        for (int eh = 0; eh < 2; ++eh) {
            const int e0 = eh * 32 + g * 8;
            f32x4 f0 = *(const f32x4*)(qp + e0);
            f32x4 f1 = *(const f32x4*)(qp + e0 + 4);
            qa[eh] = cvt8s(f0, f1, SC);
        }
    }

    f32x4 o[4] = {};                      // O: row q = g*4+j, col d = dt*16+li
    float m_run = -INFINITY, l_run = 0.0f;   // per-lane, q-row = qw + li

    const int ntiles = (qb >> 6) + 2;     // kv tiles 0..qb/64+1 — ALWAYS EVEN

    // staging indices (512 threads)
    const int skv = tid >> 3,        se0 = (tid & 7) << 3;   // K: row, 8-float chunk
    const int vkv = (tid >> 4) << 1, vd0 = (tid & 15) << 2;  // V: 2kv x 4d sub-block
    // K row permutation: rho(kv) = (kv&32) | ((kv>>2)&1)<<4 | ((kv>>3)&3)<<2 | (kv&3)
    const int rho = (skv & 32) | (((skv >> 2) & 1) << 4) | (((skv >> 3) & 3) << 2) | (skv & 3);

    const float* kp0 = K + (((size_t)(b * NS + skv)) * NH + h) * NE + se0;
    const float* vp0 = V + (((size_t)(b * NS + vkv)) * NH + h) * ND + vd0;
    const float* bp0 = Bias + (size_t)(qw + li) * NS + g * 8;   // permuted-order base

    f32x4 ka0, ka1, va0, va1;             // one stage register set (reused 2x/period)
    f32x4 bc[4], bn[4];                   // bias regs: even / odd tile

    auto issue_kv = [&](int T) {
        const float* kp = kp0 + (size_t)(T << 6) * (NH * NE);
        ka0 = ((const f32x4*)kp)[0]; ka1 = ((const f32x4*)kp)[1];
        const float* vp = vp0 + (size_t)(T << 6) * (NH * ND);
        va0 = *(const f32x4*)(vp); va1 = *(const f32x4*)(vp + NH * ND);
    };
    auto load_bias = [&](f32x4 (&bx)[4], int T) {
        const float* bp = bp0 + (T << 6);
        #pragma unroll
        for (int c = 0; c < 4; ++c)
            bx[c] = *(const f32x4*)(bp + ((c >> 1) << 5) + ((c & 1) << 2));
    };
    auto write_lds = [&](int buf) {
        *(bf16x8*)&Klds[buf][rho][se0] = cvt8(ka0, ka1);
        #pragma unroll
        for (int dd = 0; dd < 4; ++dd) {
            bf16x2 cc; cc[0] = (__bf16)va0[dd]; cc[1] = (__bf16)va1[dd];
            *(bf16x2*)&Vlds[buf][vd0 + dd][vkv ^ swz(vd0 + dd)] = cc;
        }
    };

    auto compute_tile = [&](int t, int buf, const f32x4 (&bb)[4]) {
        const int kv0 = t << 6;
        if (kv0 > qw + 15) return;        // wave-uniform causal skip
        // swapped QK^T on permuted K rows: s[c][r] = S[kv=kv0+32(c>>1)+8g+4(c&1)+r][q=qw+li]
        f32x4 s[4];
        #pragma unroll
        for (int c = 0; c < 4; ++c) {
            f32x4 acc = {};
            #pragma unroll
            for (int eh = 0; eh < 2; ++eh) {
                bf16x8 kb = *(const bf16x8*)&Klds[buf][c * 16 + li][eh * 32 + g * 8];
                acc = __builtin_amdgcn_mfma_f32_16x16x32_bf16(kb, qa[eh], acc, 0, 0, 0);
            }
            s[c] = acc;
        }
        const int lg = qw + li;
        if (kv0 + 63 > qw) {              // straddle: bias + causal select (permuted kv)
            #pragma unroll
            for (int c = 0; c < 4; ++c) {
                const int kvb = kv0 + ((c >> 1) << 5) + (g << 3) + ((c & 1) << 2);
                #pragma unroll
                for (int r = 0; r < 4; ++r)
                    s[c][r] = (kvb + r <= lg) ? fmaf(bb[c][r], SC, s[c][r]) : -INFINITY;
            }
        } else {
            #pragma unroll
            for (int c = 0; c < 4; ++c)
                #pragma unroll
                for (int r = 0; r < 4; ++r)
                    s[c][r] = fmaf(bb[c][r], SC, s[c][r]);
        }
        // row stats: 15 in-lane + 2 shuffles
        float pm = fmaxf(
            fmaxf(fmaxf(fmaxf(s[0][0],s[0][1]),fmaxf(s[0][2],s[0][3])),
                  fmaxf(fmaxf(s[1][0],s[1][1]),fmaxf(s[1][2],s[1][3]))),
            fmaxf(fmaxf(fmaxf(s[2][0],s[2][1]),fmaxf(s[2][2],s[2][3])),
                  fmaxf(fmaxf(s[3][0],s[3][1]),fmaxf(s[3][2],s[3][3]))));
        pm = fmaxf(pm, __shfl_xor(pm, 16, 64));
        pm = fmaxf(pm, __shfl_xor(pm, 32, 64));
        if (!__all(pm <= m_run + 8.0f)) {     // defer-max (T13)
            const float mn = fmaxf(m_run, pm);
            const float corr = exp2f(m_run - mn);
            m_run = mn; l_run *= corr;
            #pragma unroll
            for (int j = 0; j < 4; ++j) {
                const float cj = bpermf(g * 20 + j, corr);
                o[0][j] *= cj; o[1][j] *= cj; o[2][j] *= cj; o[3][j] *= cj;
            }
        }
        #pragma unroll
        for (int c = 0; c < 4; ++c)
            #pragma unroll
            for (int r = 0; r < 4; ++r)
                s[c][r] = exp2f(s[c][r] - m_run);
        float rs = ((s[0][0]+s[0][1])+(s[0][2]+s[0][3]))
                 + ((s[1][0]+s[1][1])+(s[1][2]+s[1][3]))
                 + ((s[2][0]+s[2][1])+(s[2][2]+s[2][3]))
                 + ((s[3][0]+s[3][1])+(s[3][2]+s[3][3]));
        rs += __shfl_xor(rs, 16, 64);
        rs += __shfl_xor(rs, 32, 64);
        l_run += rs;
        // P -> PV A-frags: direct pack (K-permutation aligned the kv order)
        u32x4 pw0, pw1;
        pw0[0] = cvtpk(s[0][0], s[0][1]); pw0[1] = cvtpk(s[0][2], s[0][3]);
        pw0[2] = cvtpk(s[1][0], s[1][1]); pw0[3] = cvtpk(s[1][2], s[1][3]);
        pw1[0] = cvtpk(s[2][0], s[2][1]); pw1[1] = cvtpk(s[2][2], s[2][3]);
        pw1[2] = cvtpk(s[3][0], s[3][1]); pw1[3] = cvtpk(s[3][2], s[3][3]);
        const bf16x8 pa0 = __builtin_bit_cast(bf16x8, pw0);
        const bf16x8 pa1 = __builtin_bit_cast(bf16x8, pw1);
        // PV: O += P @ V
        #pragma unroll
        for (int dt = 0; dt < 4; ++dt) {
            const int d = dt * 16 + li;
            bf16x8 v0 = *(const bf16x8*)&Vlds[buf][d][(g * 8) ^ swz(d)];
            bf16x8 v1 = *(const bf16x8*)&Vlds[buf][d][(32 + g * 8) ^ swz(d)];
            o[dt] = __builtin_amdgcn_mfma_f32_16x16x32_bf16(pa0, v0, o[dt], 0, 0, 0);
            o[dt] = __builtin_amdgcn_mfma_f32_16x16x32_bf16(pa1, v1, o[dt], 0, 0, 0);
        }
    };

    // ---- prologue: stage tiles 0,1; bias 0,1 ----
    issue_kv(0);
    load_bias(bc, 0);
    write_lds(0);
    issue_kv(1);
    load_bias(bn, 1);
    write_lds(1);
    __syncthreads();

    // ---- main loop: 2 tiles per period, ONE barrier per period ----
    for (int t = 0; t < ntiles; t += 2) {
        const bool more = (t + 2 < ntiles);
        if (more) issue_kv(t + 2);
        compute_tile(t, t & 3, bc);
        if (more) {
            write_lds((t + 2) & 3);       // cover = compute(t)
            issue_kv(t + 3);
            load_bias(bc, t + 2);         // bc dead after compute(t)
        }
        compute_tile(t + 1, (t + 1) & 3, bn);
        if (more) {
            write_lds((t + 3) & 3);       // cover = compute(t+1)
            load_bias(bn, t + 3);
            __syncthreads();              // one barrier per 2 tiles
        }
    }

    // ---- epilogue: transport l to O layout, normalize, store fp32 ----
    #pragma unroll
    for (int j = 0; j < 4; ++j) {
        const float lj = bpermf(g * 20 + j, l_run);   // src lane (g, li=g*4+j)
        const float inv = 1.0f / lj;
        const int lgq = qw + g * 4 + j;
        float* op = Out + (((size_t)(b * NL + lgq)) * NH + h) * ND + li;
        op[0]  = o[0][j] * inv;
        op[16] = o[1][j] * inv;
        op[32] = o[2][j] * inv;
        op[48] = o[3][j] * inv;
    }
}

extern "C" void kernel_launch(void* const* d_in, const int* in_sizes, int n_in,
                              void* d_out, int out_size, void* d_ws, size_t ws_size,
                              hipStream_t stream)
{
    const float* Q    = (const float*)d_in[0];
    const float* K    = (const float*)d_in[1];
    const float* V    = (const float*)d_in[2];
    const float* Bias = (const float*)d_in[3];
    // d_in[4] (attn_mask) is the static triu(k=1) causal mask - handled analytically.
    float* Out = (float*)d_out;
    dim3 grid(512);                  // remapped in-kernel (complementary pairing)
    dim3 block(512);
    fa_fwd<<<grid, block, 0, stream>>>(Q, K, V, Bias, Out);
}